// Round 5
// baseline (29.038 us; speedup 1.0000x reference)
//
#include <hip/hip_runtime.h>
#include <cstddef>

// Problem constants: B=2, H=W=128, C=16, F=16, px=py=8, sx=sy=4 -> lx=ly=2
#define HH 128
#define WW 128
#define CC 16

// Single fused kernel. Block = (b, ch, 32x32 pixel tile). 256 threads.
// Phase 1: 11x11 halo cells (4x4 non-overlap partial sums of b and pet*b) -> LDS.
//          Cell gi covers rows [4*gi-2, 4*gi+2), zero-clipped to [0,128).
//          Tile ty needs gi in [8ty-1, 8ty+9]; out-of-grid cells sum to zero.
// Phase 2: 10x10 patch ratios (divide_no_nan of 2x2-cell window sums) -> LDS.
// Phase 3: 4 pixels/thread:
//          out = 0.25 * sum_f bfe[...,f] * (sum of <=4 valid local ratios);
//          il=0 valid iff y<=125, local pi = 2*((dy+2)>>3)+1
//          il=1 valid iff y>=2,   local pi = 2*((dy-2)>>3)+2 (arith shift)
__global__ __launch_bounds__(256) void fused32_kernel(
    const float*  __restrict__ pet,   // (B,128,128,16)
    const float4* __restrict__ bfe4,  // (B,128,128,16,16) as float4 over f
    float* __restrict__ out)          // (B,128,128,16)
{
    __shared__ float4 sD[11 * 11 * 4];   // 7744 B
    __shared__ float4 sK[11 * 11 * 4];   // 7744 B
    __shared__ float4 sR[10 * 10 * 4];   // 6400 B

    int bid = blockIdx.x;
    int tx = bid & 3;
    int ty = (bid >> 2) & 3;
    int ch = (bid >> 4) & 15;
    int b  = bid >> 8;

    int tid = threadIdx.x;
    int y0 = 32 * ty, x0 = 32 * tx;
    int gi0 = 8 * ty - 1, gj0 = 8 * tx - 1;

    // ---------------- Phase 1: halo cells ----------------
    for (int item = tid; item < 484; item += 256) {   // 11*11 cells * 4 f4
        int f4 = item & 3;
        int cc = item >> 2;           // 0..120
        int cj = cc % 11, ci = cc / 11;
        int r0 = 4 * (gi0 + ci) - 2;
        int s0 = 4 * (gj0 + cj) - 2;
        float4 d = make_float4(0.f, 0.f, 0.f, 0.f);
        float4 k = make_float4(0.f, 0.f, 0.f, 0.f);
        if (r0 >= 0 && r0 + 4 <= HH && s0 >= 0 && s0 + 4 <= WW) {
            // interior fast path: no per-load clipping
            #pragma unroll
            for (int p = 0; p < 4; ++p) {
                #pragma unroll
                for (int q = 0; q < 4; ++q) {
                    int pix = (b * HH + r0 + p) * WW + (s0 + q);
                    float4 bv = bfe4[(size_t)pix * 64 + ch * 4 + f4];
                    float  pv = pet[(size_t)pix * CC + ch];
                    d.x += bv.x;      d.y += bv.y;      d.z += bv.z;      d.w += bv.w;
                    k.x += pv * bv.x; k.y += pv * bv.y; k.z += pv * bv.z; k.w += pv * bv.w;
                }
            }
        } else {
            #pragma unroll
            for (int p = 0; p < 4; ++p) {
                int r = r0 + p;
                if ((unsigned)r >= (unsigned)HH) continue;
                #pragma unroll
                for (int q = 0; q < 4; ++q) {
                    int s = s0 + q;
                    if ((unsigned)s >= (unsigned)WW) continue;
                    int pix = (b * HH + r) * WW + s;
                    float4 bv = bfe4[(size_t)pix * 64 + ch * 4 + f4];
                    float  pv = pet[(size_t)pix * CC + ch];
                    d.x += bv.x;      d.y += bv.y;      d.z += bv.z;      d.w += bv.w;
                    k.x += pv * bv.x; k.y += pv * bv.y; k.z += pv * bv.z; k.w += pv * bv.w;
                }
            }
        }
        sD[item] = d;
        sK[item] = k;
    }
    __syncthreads();

    // ---------------- Phase 2: ratios ----------------
    for (int item = tid; item < 400; item += 256) {   // 10*10 patches * 4 f4
        int f4 = item & 3;
        int pc = item >> 2;           // 0..99
        int pj = pc % 10, pi = pc / 10;
        float4 D = make_float4(0.f, 0.f, 0.f, 0.f);
        float4 K = make_float4(0.f, 0.f, 0.f, 0.f);
        #pragma unroll
        for (int di = 0; di < 2; ++di) {
            #pragma unroll
            for (int dj = 0; dj < 2; ++dj) {
                int cc = (pi + di) * 11 + (pj + dj);
                float4 cd = sD[cc * 4 + f4];
                float4 ck = sK[cc * 4 + f4];
                D.x += cd.x; D.y += cd.y; D.z += cd.z; D.w += cd.w;
                K.x += ck.x; K.y += ck.y; K.z += ck.z; K.w += ck.w;
            }
        }
        float4 rv;
        rv.x = (D.x != 0.f) ? K.x / D.x : 0.f;
        rv.y = (D.y != 0.f) ? K.y / D.y : 0.f;
        rv.z = (D.z != 0.f) ? K.z / D.z : 0.f;
        rv.w = (D.w != 0.f) ? K.w / D.w : 0.f;
        sR[item] = rv;                // (pi*10+pj)*4 + f4 == item
    }
    __syncthreads();

    // ---------------- Phase 3: output, 4 pixels/thread ----------------
    #pragma unroll
    for (int k3 = 0; k3 < 4; ++k3) {
        int p  = tid + k3 * 256;      // 0..1023
        int dy = p >> 5, dx = p & 31;
        int y = y0 + dy, x = x0 + dx;

        float rs[16];
        #pragma unroll
        for (int i = 0; i < 16; ++i) rs[i] = 0.f;

        #pragma unroll
        for (int il = 0; il < 2; ++il) {
            bool vy = il ? (y >= 2) : (y <= 125);
            int pi = il ? (2 * ((dy - 2) >> 3) + 2)
                        : (2 * ((dy + 2) >> 3) + 1);
            #pragma unroll
            for (int jl = 0; jl < 2; ++jl) {
                bool vx = jl ? (x >= 2) : (x <= 125);
                int pj = jl ? (2 * ((dx - 2) >> 3) + 2)
                            : (2 * ((dx + 2) >> 3) + 1);
                if (vy && vx) {
                    int base = (pi * 10 + pj) * 4;
                    #pragma unroll
                    for (int v = 0; v < 4; ++v) {
                        float4 rv = sR[base + v];
                        rs[4*v+0] += rv.x; rs[4*v+1] += rv.y;
                        rs[4*v+2] += rv.z; rs[4*v+3] += rv.w;
                    }
                }
            }
        }

        int pix = (b * HH + y) * WW + x;
        const float4* bp = bfe4 + (size_t)pix * 64 + ch * 4;
        float acc = 0.f;
        #pragma unroll
        for (int v = 0; v < 4; ++v) {
            float4 bv = bp[v];
            acc += rs[4*v+0] * bv.x + rs[4*v+1] * bv.y
                 + rs[4*v+2] * bv.z + rs[4*v+3] * bv.w;
        }
        out[(size_t)pix * CC + ch] = 0.25f * acc;
    }
}

extern "C" void kernel_launch(void* const* d_in, const int* in_sizes, int n_in,
                              void* d_out, int out_size, void* d_ws, size_t ws_size,
                              hipStream_t stream) {
    // inputs: 0=mr (unused), 1=pet (B,128,128,16), 2=b_features (B,128,128,16,16)
    const float* pet = (const float*)d_in[1];
    const float* bfe = (const float*)d_in[2];
    int B = in_sizes[1] / (HH * WW * CC);   // = 2

    // grid: b * ch * (4x4 tiles of 32x32) = B*16*16 = 512
    int grid = B * 16 * 16;
    fused32_kernel<<<grid, 256, 0, stream>>>(pet, (const float4*)bfe, (float*)d_out);
}